// Round 1
// baseline (753.846 us; speedup 1.0000x reference)
//
#include <hip/hip_runtime.h>
#include <stdint.h>

#define F_DIM 321
#define O_DIM 720
#define I_DIM 512
#define B_DIM 32

typedef __attribute__((ext_vector_type(8))) short short8;   // 8 bf16 = 4 VGPRs
typedef __attribute__((ext_vector_type(4))) float f32x4;
typedef __attribute__((ext_vector_type(4))) uint32_t u32x4;

// Round-to-nearest-even fp32 -> bf16, packed pairwise into a dword.
__device__ __forceinline__ uint32_t rne_pack2(float lo, float hi) {
  uint32_t a = __builtin_bit_cast(uint32_t, lo);
  uint32_t b = __builtin_bit_cast(uint32_t, hi);
  a += 0x7FFFu + ((a >> 16) & 1u);
  b += 0x7FFFu + ((b >> 16) & 1u);
  return (a >> 16) | (b & 0xFFFF0000u);
}

// Kernel 1: xn = x*inv + shift (BN eval affine), cast to bf16, packed in
// A-fragment-native layout: ws[f][iblk(64)][b(32)] = 16B holding 8 consecutive
// i-values (i = iblk*8 + j) for that (b, f). Main kernel A-frag = 1 dwordx4.
__global__ void __launch_bounds__(256) xn_pack_kernel(
    const float* __restrict__ x, const float* __restrict__ gamma,
    const float* __restrict__ beta, const float* __restrict__ rmean,
    const float* __restrict__ rvar, u32x4* __restrict__ ws) {
  __shared__ float tile[8 * F_DIM];
  const int iblk = blockIdx.x;  // 0..63  (i-octet)
  const int b    = blockIdx.y;  // 0..31
  const float* src = x + ((size_t)b * I_DIM + (size_t)iblk * 8) * F_DIM;
  for (int idx = threadIdx.x; idx < 8 * F_DIM; idx += 256)
    tile[idx] = src[idx];                       // contiguous, coalesced
  __syncthreads();
  for (int f = threadIdx.x; f < F_DIM; f += 256) {
    float inv = gamma[f] * rsqrtf(rvar[f] + 1e-5f);
    float sh  = beta[f] - rmean[f] * inv;
    float v[8];
#pragma unroll
    for (int j = 0; j < 8; ++j) v[j] = fmaf(tile[j * F_DIM + f], inv, sh);
    u32x4 pk;
    pk.x = rne_pack2(v[0], v[1]);
    pk.y = rne_pack2(v[2], v[3]);
    pk.z = rne_pack2(v[4], v[5]);
    pk.w = rne_pack2(v[6], v[7]);
    ws[(size_t)f * 2048 + iblk * 32 + b] = pk;  // 16B store, L2-combined
  }
}

// Kernel 2: per-f GEMM via 16x16x32 bf16 MFMA.
//   wave -> (m-tile = w&1, n-tile = w>>1 within 32-o block), G=4 f's per block.
//   A-frag: coalesced dwordx4 from packed xn (L2-resident, reused 23x).
//   B-frag: direct global loads of W rows (8 consecutive i per lane, full
//           128B-line consumption per fragment pair), RNE-cast to bf16 inline.
__global__ void __launch_bounds__(256) linear_bn_kernel(
    const float* __restrict__ Wt, const float* __restrict__ bias,
    const u32x4* __restrict__ xn, float* __restrict__ out) {
  const int lane = threadIdx.x & 63;
  const int wv   = threadIdx.x >> 6;
  const int quad = lane >> 4;
  const int t16  = lane & 15;
  const int m0   = (wv & 1) << 4;                    // b-row tile: 0 or 16
  const int o0   = blockIdx.x * 32 + ((wv >> 1) << 4);
  if (o0 >= O_DIM) return;                           // whole-wave OOB (bx=22)
  const int fb = blockIdx.y * 4;
  const int nf = min(4, F_DIM - fb);                 // last group has 1 f
  const int o  = o0 + t16;

  f32x4 acc[4];
#pragma unroll
  for (int ff = 0; ff < 4; ++ff) {
    float bv = 0.0f;
    if (ff < nf) bv = bias[(size_t)(fb + ff) * O_DIM + o];
    acc[ff] = (f32x4){bv, bv, bv, bv};               // bias indep of b-row
  }

  for (int kk = 0; kk < 16; ++kk) {                  // K = 16 steps of 32
    const int iblk = kk * 4 + quad;
#pragma unroll
    for (int ff = 0; ff < 4; ++ff) {
      if (ff < nf) {
        const int f = fb + ff;
        // A[m = lane&15][k = quad*8 + j]
        u32x4 av = xn[(size_t)f * 2048 + iblk * 32 + m0 + t16];
        short8 afrag = __builtin_bit_cast(short8, av);
        // B[k = quad*8 + j][n = lane&15]  <- W[f][o][i], i contiguous
        const float* pb =
            Wt + ((size_t)f * O_DIM + o) * I_DIM + kk * 32 + quad * 8;
        f32x4 w0 = *(const f32x4*)pb;
        f32x4 w1 = *(const f32x4*)(pb + 4);
        u32x4 bu;
        bu.x = rne_pack2(w0.x, w0.y);
        bu.y = rne_pack2(w0.z, w0.w);
        bu.z = rne_pack2(w1.x, w1.y);
        bu.w = rne_pack2(w1.z, w1.w);
        short8 bfrag = __builtin_bit_cast(short8, bu);
        acc[ff] =
            __builtin_amdgcn_mfma_f32_16x16x32_bf16(afrag, bfrag, acc[ff], 0, 0, 0);
      }
    }
  }

  // C/D: col = lane&15 (o), row = quad*4 + reg (b). Scalar dword stores:
  // out f-stride is 321 (odd) so 16B stores would be misaligned anyway.
#pragma unroll
  for (int ff = 0; ff < 4; ++ff) {
    if (ff < nf) {
#pragma unroll
      for (int r = 0; r < 4; ++r) {
        const int brow = m0 + quad * 4 + r;
        out[((size_t)brow * O_DIM + o) * F_DIM + fb + ff] = acc[ff][r];
      }
    }
  }
}

extern "C" void kernel_launch(void* const* d_in, const int* in_sizes, int n_in,
                              void* d_out, int out_size, void* d_ws, size_t ws_size,
                              hipStream_t stream) {
  const float* x     = (const float*)d_in[0];
  const float* W     = (const float*)d_in[1];
  const float* b     = (const float*)d_in[2];
  const float* gamma = (const float*)d_in[3];
  const float* beta  = (const float*)d_in[4];
  const float* rmean = (const float*)d_in[5];
  const float* rvar  = (const float*)d_in[6];
  u32x4* ws = (u32x4*)d_ws;  // needs 321*2048*16 B = 10.5 MB

  xn_pack_kernel<<<dim3(64, 32), 256, 0, stream>>>(x, gamma, beta, rmean, rvar, ws);
  linear_bn_kernel<<<dim3(23, 81), 256, 0, stream>>>(W, b, ws, (float*)d_out);
}

// Round 2
// 746.957 us; speedup vs baseline: 1.0092x; 1.0092x over previous
//
#include <hip/hip_runtime.h>
#include <stdint.h>

#define F_DIM 321
#define O_DIM 720
#define I_DIM 512
#define B_DIM 32
#define G_F 8   // f's per block in the GEMM kernel

typedef __attribute__((ext_vector_type(8))) short short8;   // 8 bf16 = 4 VGPRs
typedef __attribute__((ext_vector_type(4))) float f32x4;
typedef __attribute__((ext_vector_type(4))) uint32_t u32x4;

// Round-to-nearest-even fp32 -> bf16, packed pairwise into a dword.
__device__ __forceinline__ uint32_t rne_pack2(float lo, float hi) {
  uint32_t a = __builtin_bit_cast(uint32_t, lo);
  uint32_t b = __builtin_bit_cast(uint32_t, hi);
  a += 0x7FFFu + ((a >> 16) & 1u);
  b += 0x7FFFu + ((b >> 16) & 1u);
  return (a >> 16) | (b & 0xFFFF0000u);
}

// Kernel 1 (unchanged, verified R1): xn = x*inv + shift, bf16, A-frag-native:
// ws[f][iblk(64)][b(32)] = 16B = 8 consecutive i for that (b,f).
__global__ void __launch_bounds__(256) xn_pack_kernel(
    const float* __restrict__ x, const float* __restrict__ gamma,
    const float* __restrict__ beta, const float* __restrict__ rmean,
    const float* __restrict__ rvar, u32x4* __restrict__ ws) {
  __shared__ float tile[8 * F_DIM];
  const int iblk = blockIdx.x;  // 0..63
  const int b    = blockIdx.y;  // 0..31
  const float* src = x + ((size_t)b * I_DIM + (size_t)iblk * 8) * F_DIM;
  for (int idx = threadIdx.x; idx < 8 * F_DIM; idx += 256)
    tile[idx] = src[idx];
  __syncthreads();
  for (int f = threadIdx.x; f < F_DIM; f += 256) {
    float inv = gamma[f] * rsqrtf(rvar[f] + 1e-5f);
    float sh  = beta[f] - rmean[f] * inv;
    float v[8];
#pragma unroll
    for (int j = 0; j < 8; ++j) v[j] = fmaf(tile[j * F_DIM + f], inv, sh);
    u32x4 pk;
    pk.x = rne_pack2(v[0], v[1]);
    pk.y = rne_pack2(v[2], v[3]);
    pk.z = rne_pack2(v[4], v[5]);
    pk.w = rne_pack2(v[6], v[7]);
    ws[(size_t)f * 2048 + iblk * 32 + b] = pk;
  }
}

// Kernel 2 v2: W staged through LDS so HBM sees contiguous 64-KB bursts
// per (block, f) instead of ~10^5 concurrent 128-B streams (R1: ~2 TB/s eff).
//
// LDS granule g (16 B, one B-frag octet) = kk*128 + ntile*64 + t16*4 + quad
//  -> both ds_write (staging) and ds_read (B-frag) touch 64 consecutive
//     granules per wave instruction (dense b128 fast path, m134).
// Register-prefetch of next f's tile overlaps global latency with MFMA.
__global__ void __launch_bounds__(256) linear_bn_kernel(
    const float* __restrict__ Wt, const float* __restrict__ bias,
    const u32x4* __restrict__ xn, float* __restrict__ out) {
  __shared__ u32x4 lds[2048];  // 32 KB bf16 W-tile: 32 o x 512 i
  const int tid  = threadIdx.x;
  const int lane = tid & 63;
  const int wv   = tid >> 6;
  const int quad = lane >> 4;
  const int t16  = lane & 15;
  const int mtile = wv & 1;        // compute: b-half
  const int ntile = wv >> 1;       // compute: o-half
  const int kkh   = wv >> 1;       // staging: k-half (any bijection works)
  const int ntS   = wv & 1;        // staging: o-half
  const int o0 = blockIdx.x * 32;
  const int fb = blockIdx.y * G_F;
  const int nf = min(G_F, F_DIM - fb);   // tail group (fb=320) has nf=1
  // staging coords: this thread loads row oS, 32-B chunk (kkh*8+j)*4+sQuad
  const int sRow  = ntS * 16 + (lane >> 2);
  const int sQuad = lane & 3;
  const int oS = min(o0 + sRow, O_DIM - 1);  // clamp (bx=22 rows 720..735)
  const int oC = o0 + ntile * 16 + t16;      // compute column (guarded)

  f32x4 acc[G_F];
#pragma unroll
  for (int ff = 0; ff < G_F; ++ff) {
    float bv = 0.0f;
    if (ff < nf && oC < O_DIM) bv = bias[(size_t)(fb + ff) * O_DIM + oC];
    acc[ff] = (f32x4){bv, bv, bv, bv};
  }

  u32x4 pk[8];
  auto stage_load = [&](int f) {
    // 16 KB per wave, contiguous with its sibling waves: DRAM-friendly burst
    const float* base =
        Wt + ((size_t)f * O_DIM + oS) * I_DIM + kkh * 256 + sQuad * 8;
#pragma unroll
    for (int j = 0; j < 8; ++j) {
      f32x4 a = *(const f32x4*)(base + j * 32);
      f32x4 b = *(const f32x4*)(base + j * 32 + 4);
      u32x4 p;
      p.x = rne_pack2(a.x, a.y);
      p.y = rne_pack2(a.z, a.w);
      p.z = rne_pack2(b.x, b.y);
      p.w = rne_pack2(b.z, b.w);
      pk[j] = p;
    }
  };

  stage_load(fb);
#pragma unroll
  for (int ff = 0; ff < G_F; ++ff) {
    if (ff >= nf) break;               // nf is block-uniform: barrier-safe
    __syncthreads();                   // LDS free (previous compute done)
#pragma unroll
    for (int j = 0; j < 8; ++j)
      lds[(kkh * 8 + j) * 128 + ntS * 64 + lane] = pk[j];  // dense 1-KB write
    __syncthreads();
    if (ff + 1 < nf) stage_load(fb + ff + 1);  // prefetch overlaps compute
    const int f = fb + ff;
    const u32x4* xf = xn + (size_t)f * 2048 + mtile * 16 + t16;
#pragma unroll
    for (int kk = 0; kk < 16; ++kk) {
      u32x4 av = xf[(kk * 4 + quad) * 32];                      // A: L2-res
      u32x4 bv = lds[kk * 128 + ntile * 64 + (t16 << 2) + quad]; // dense read
      acc[ff] = __builtin_amdgcn_mfma_f32_16x16x32_bf16(
          __builtin_bit_cast(short8, av), __builtin_bit_cast(short8, bv),
          acc[ff], 0, 0, 0);
    }
  }

  // Epilogue: C/D col = t16 (o), row = quad*4+r (b). ff-inner store order
  // gives 8 consecutive f-dwords per (b,o) -> L2 merges into 32-B runs.
  if (oC < O_DIM) {
#pragma unroll
    for (int r = 0; r < 4; ++r) {
      const int brow = mtile * 16 + quad * 4 + r;
      float* po = out + ((size_t)brow * O_DIM + oC) * F_DIM + fb;
#pragma unroll
      for (int ff = 0; ff < G_F; ++ff)
        if (ff < nf) po[ff] = acc[ff][r];
    }
  }
}

extern "C" void kernel_launch(void* const* d_in, const int* in_sizes, int n_in,
                              void* d_out, int out_size, void* d_ws, size_t ws_size,
                              hipStream_t stream) {
  const float* x     = (const float*)d_in[0];
  const float* W     = (const float*)d_in[1];
  const float* b     = (const float*)d_in[2];
  const float* gamma = (const float*)d_in[3];
  const float* beta  = (const float*)d_in[4];
  const float* rmean = (const float*)d_in[5];
  const float* rvar  = (const float*)d_in[6];
  u32x4* ws = (u32x4*)d_ws;  // 321*2048*16 B = 10.5 MB << ws_size

  xn_pack_kernel<<<dim3(64, 32), 256, 0, stream>>>(x, gamma, beta, rmean, rvar, ws);
  linear_bn_kernel<<<dim3(23, 41), 256, 0, stream>>>(W, b, ws, (float*)d_out);
}